// Round 4
// baseline (634.124 us; speedup 1.0000x reference)
//
#include <hip/hip_runtime.h>
#include <hip/hip_bf16.h>

// Problem dims
#define BB 64
#define TT 128
#define FIN 12
#define HH 128
#define GG 512  // 4*H

#define LOG2E 1.4426950408889634f
#define TWO_LOG2E 2.8853900817779268f

__device__ __forceinline__ float fexp2(float x) { return __builtin_amdgcn_exp2f(x); }
__device__ __forceinline__ float frcp(float x)  { return __builtin_amdgcn_rcpf(x); }

// tanh(x) = 1 - 2/(1+e^{2x}); correct limits at +/-inf via exp2->{inf,0}
__device__ __forceinline__ float tanh_f(float x) {
  return 1.0f - 2.0f * frcp(1.0f + fexp2(TWO_LOG2E * x));
}
__device__ __forceinline__ float sigm_f(float x) {
  return frcp(1.0f + fexp2(-LOG2E * x));
}

#define FMA4S(acc, s, v) do { \
  acc.x = fmaf((s), (v).x, acc.x); \
  acc.y = fmaf((s), (v).y, acc.y); \
  acc.z = fmaf((s), (v).z, acc.z); \
  acc.w = fmaf((s), (v).w, acc.w); } while (0)

// ---------------------------------------------------------------------------
// K1 v4: encoder + decoder LSTM. One block per batch, 256 threads (4 waves,
// 1/SIMD). Each thread owns TWO complete gate rows (full K=128 dot product:
// 64 float4 weights resident in VGPRs; launch_bounds(256,1) gives the 512-VGPR
// budget -- unlike R1's (512,2) 128-cap which spilled). No cross-lane
// reduction: even lane -> gates (i,g) of h-index j, odd lane -> gates (f,o)
// of the same j; the single i*g~ exchange is shfl_xor(.,1) = quad-perm DPP
// (VALU, not a DS op). 1 barrier/step; DS ops per wave-step = 32 broadcast
// b128 h-reads + 3 x-reads + 1 h-write.
// R1-R3 lesson: LDS instruction count + swizzle latency + barriers bound this
// kernel (~2200 cyc/step invariant across designs), not LDS bytes.
// ---------------------------------------------------------------------------
__global__ __launch_bounds__(256, 1) void lstm_kernel(
    const float* __restrict__ x,
    const float* __restrict__ eWih, const float* __restrict__ eWhh, const float* __restrict__ eb,
    const float* __restrict__ dWih, const float* __restrict__ dWhh, const float* __restrict__ db,
    float* __restrict__ encH, float* __restrict__ decH)
{
  const int b    = blockIdx.x;
  const int tid  = threadIdx.x;   // 0..255
  const int lane = tid & 63;
  const int wv   = tid >> 6;      // wave 0..3
  const int p    = lane & 1;      // 0: gates (i,g), 1: gates (f,o)
  const int j    = wv * 32 + (lane >> 1);  // h-index 0..127

  __shared__ __align__(16) float xs[TT * FIN];  // 6 KB
  __shared__ __align__(16) float hbuf[2][HH];   // 1 KB, double-buffered

  // stage x
  {
    const float4* src = (const float4*)(x + (size_t)b * TT * FIN);
    ((float4*)xs)[tid] = src[tid];
    if (tid < 128) ((float4*)xs)[256 + tid] = src[256 + tid];
  }
  if (tid < HH) { hbuf[0][tid] = 0.0f; hbuf[1][tid] = 0.0f; }
  float c = 0.0f;  // live in odd lanes

  const int row_a = p * HH + j;        // i (p=0) or f (p=1)
  const int row_b = (2 + p) * HH + j;  // g (p=0) or o (p=1)
  const float kact = p ? -LOG2E : TWO_LOG2E;  // zb activation: sigm vs tanh

  int ts = 0;
  #pragma unroll 1
  for (int phase = 0; phase < 2; ++phase) {
    const float* Wih  = phase ? dWih : eWih;
    const float* Whh  = phase ? dWhh : eWhh;
    const float* bias = phase ? db : eb;
    float* Hout       = phase ? decH : encH;

    // full gate rows in VGPRs: 64 float4 = 256 VGPRs
    float4 wa[32], wb[32];
    #pragma unroll
    for (int k = 0; k < 32; ++k) {
      wa[k] = *(const float4*)(Whh + (size_t)row_a * HH + 4 * k);
      wb[k] = *(const float4*)(Whh + (size_t)row_b * HH + 4 * k);
    }
    float4 xwa[3], xwb[3];
    #pragma unroll
    for (int k = 0; k < 3; ++k) {
      xwa[k] = *(const float4*)(Wih + (size_t)row_a * FIN + 4 * k);
      xwb[k] = *(const float4*)(Wih + (size_t)row_b * FIN + 4 * k);
    }
    const float bza = bias[row_a];
    const float bzb = bias[row_b];

    #pragma unroll 1
    for (int t = 0; t < TT; ++t, ++ts) {
      __syncthreads();  // h(t) ready in hbuf[ts&1]
      const float* hb = hbuf[ts & 1];

      float a0 = bza, a1 = 0.f, a2 = 0.f, a3 = 0.f;
      float b0 = bzb, b1 = 0.f, b2 = 0.f, b3 = 0.f;
      #pragma unroll
      for (int k = 0; k < 32; k += 4) {
        float4 h0 = *(const float4*)&hb[4 * k];       // broadcast reads
        float4 h1 = *(const float4*)&hb[4 * k + 4];
        float4 h2 = *(const float4*)&hb[4 * k + 8];
        float4 h3 = *(const float4*)&hb[4 * k + 12];
        a0 = fmaf(h0.x, wa[k].x, a0);   a1 = fmaf(h0.y, wa[k].y, a1);
        a2 = fmaf(h0.z, wa[k].z, a2);   a3 = fmaf(h0.w, wa[k].w, a3);
        b0 = fmaf(h0.x, wb[k].x, b0);   b1 = fmaf(h0.y, wb[k].y, b1);
        b2 = fmaf(h0.z, wb[k].z, b2);   b3 = fmaf(h0.w, wb[k].w, b3);
        a0 = fmaf(h1.x, wa[k+1].x, a0); a1 = fmaf(h1.y, wa[k+1].y, a1);
        a2 = fmaf(h1.z, wa[k+1].z, a2); a3 = fmaf(h1.w, wa[k+1].w, a3);
        b0 = fmaf(h1.x, wb[k+1].x, b0); b1 = fmaf(h1.y, wb[k+1].y, b1);
        b2 = fmaf(h1.z, wb[k+1].z, b2); b3 = fmaf(h1.w, wb[k+1].w, b3);
        a0 = fmaf(h2.x, wa[k+2].x, a0); a1 = fmaf(h2.y, wa[k+2].y, a1);
        a2 = fmaf(h2.z, wa[k+2].z, a2); a3 = fmaf(h2.w, wa[k+2].w, a3);
        b0 = fmaf(h2.x, wb[k+2].x, b0); b1 = fmaf(h2.y, wb[k+2].y, b1);
        b2 = fmaf(h2.z, wb[k+2].z, b2); b3 = fmaf(h2.w, wb[k+2].w, b3);
        a0 = fmaf(h3.x, wa[k+3].x, a0); a1 = fmaf(h3.y, wa[k+3].y, a1);
        a2 = fmaf(h3.z, wa[k+3].z, a2); a3 = fmaf(h3.w, wa[k+3].w, a3);
        b0 = fmaf(h3.x, wb[k+3].x, b0); b1 = fmaf(h3.y, wb[k+3].y, b1);
        b2 = fmaf(h3.z, wb[k+3].z, b2); b3 = fmaf(h3.w, wb[k+3].w, b3);
      }
      // x contribution (uniform broadcast reads)
      {
        const float4* xt = (const float4*)(xs + t * FIN);
        float4 x0 = xt[0], x1 = xt[1], x2 = xt[2];
        a0 = fmaf(x0.x, xwa[0].x, a0); a1 = fmaf(x0.y, xwa[0].y, a1);
        a2 = fmaf(x0.z, xwa[0].z, a2); a3 = fmaf(x0.w, xwa[0].w, a3);
        a0 = fmaf(x1.x, xwa[1].x, a0); a1 = fmaf(x1.y, xwa[1].y, a1);
        a2 = fmaf(x1.z, xwa[1].z, a2); a3 = fmaf(x1.w, xwa[1].w, a3);
        a0 = fmaf(x2.x, xwa[2].x, a0); a1 = fmaf(x2.y, xwa[2].y, a1);
        a2 = fmaf(x2.z, xwa[2].z, a2); a3 = fmaf(x2.w, xwa[2].w, a3);
        b0 = fmaf(x0.x, xwb[0].x, b0); b1 = fmaf(x0.y, xwb[0].y, b1);
        b2 = fmaf(x0.z, xwb[0].z, b2); b3 = fmaf(x0.w, xwb[0].w, b3);
        b0 = fmaf(x1.x, xwb[1].x, b0); b1 = fmaf(x1.y, xwb[1].y, b1);
        b2 = fmaf(x1.z, xwb[1].z, b2); b3 = fmaf(x1.w, xwb[1].w, b3);
        b0 = fmaf(x2.x, xwb[2].x, b0); b1 = fmaf(x2.y, xwb[2].y, b1);
        b2 = fmaf(x2.z, xwb[2].z, b2); b3 = fmaf(x2.w, xwb[2].w, b3);
      }
      float za = (a0 + a1) + (a2 + a3);
      float zb = (b0 + b1) + (b2 + b3);

      // activations (branchless):
      // sa = sigmoid(za) -> even: zi, odd: zf
      // vb: even: tanh(zb) = 1-2r, r = rcp(1+exp2(2L*zb));
      //     odd:  sigm(zb) = r,    r = rcp(1+exp2(-L*zb))
      float sa = sigm_f(za);
      float r  = frcp(1.0f + fexp2(kact * zb));
      float vb = p ? r : 1.0f - 2.0f * r;
      float u  = sa * vb;                 // even lanes: i * g~
      float ux = __shfl_xor(u, 1, 64);    // odd lanes receive i*g~ (DPP)
      if (p) {
        c = fmaf(sa, c, ux);              // c = f*c + i*g~
        float hn = vb * tanh_f(c);        // h = o * tanh(c)
        hbuf[(ts + 1) & 1][j] = hn;
        Hout[((size_t)b * TT + t) * HH + j] = hn;
      }
    }
  }
}

// ---------------------------------------------------------------------------
// K2: A[b,s,h] = decH[b,s,:]·W1[h,:] + attn_b[h]   (m==0)
//     P[b,t,h] = encH[b,t,:]·W2[h,:]               (m==1)
// grid 1024 = (8 row-tiles x 64 b x 2 m), 256 threads, k-halved LDS W^T.
// ---------------------------------------------------------------------------
__global__ __launch_bounds__(256, 2) void proj_kernel(
    const float* __restrict__ encH, const float* __restrict__ decH,
    const float* __restrict__ attnW, const float* __restrict__ attnb,
    float* __restrict__ Abuf, float* __restrict__ Pbuf)
{
  const int m  = blockIdx.x & 1;
  const int b  = (blockIdx.x >> 1) & 63;
  const int r0 = (blockIdx.x >> 7) * 16;
  const int tid = threadIdx.x;

  __shared__ __align__(16) float WT[64 * 128];  // 32 KB: W^T for a k-half
  __shared__ __align__(16) float Xt[16 * 128];  // 8 KB

  const float* X = (m ? encH : decH) + ((size_t)b * TT + r0) * HH;
  const float* W = attnW + (m ? HH : 0);

  ((float4*)Xt)[tid]       = ((const float4*)X)[tid];
  ((float4*)Xt)[256 + tid] = ((const float4*)X)[256 + tid];

  const int hq = tid & 31, rr = tid >> 5;
  const int h0 = 4 * hq;

  float4 acc0, acc1;
  if (m == 0) { acc0 = *(const float4*)(attnb + h0); acc1 = acc0; }
  else        { acc0 = make_float4(0.f, 0.f, 0.f, 0.f); acc1 = acc0; }

  for (int kb = 0; kb < 2; ++kb) {
    __syncthreads();  // protect WT overwrite
    {
      int h = tid >> 1, koff = (tid & 1) * 32;
      #pragma unroll
      for (int j = 0; j < 8; ++j) {
        float4 v = *(const float4*)(W + h * 256 + kb * 64 + koff + 4 * j);
        int kp = koff + 4 * j;
        WT[(kp + 0) * 128 + h] = v.x;
        WT[(kp + 1) * 128 + h] = v.y;
        WT[(kp + 2) * 128 + h] = v.z;
        WT[(kp + 3) * 128 + h] = v.w;
      }
    }
    __syncthreads();
    const float* xr0 = Xt + (2 * rr) * 128 + kb * 64;
    const float* xr1 = xr0 + 128;
    #pragma unroll
    for (int k4 = 0; k4 < 64; k4 += 4) {
      float4 xa = *(const float4*)(xr0 + k4);
      float4 xb = *(const float4*)(xr1 + k4);
      float4 w0 = *(const float4*)&WT[(k4 + 0) * 128 + h0];
      float4 w1 = *(const float4*)&WT[(k4 + 1) * 128 + h0];
      float4 w2 = *(const float4*)&WT[(k4 + 2) * 128 + h0];
      float4 w3 = *(const float4*)&WT[(k4 + 3) * 128 + h0];
      FMA4S(acc0, xa.x, w0); FMA4S(acc0, xa.y, w1);
      FMA4S(acc0, xa.z, w2); FMA4S(acc0, xa.w, w3);
      FMA4S(acc1, xb.x, w0); FMA4S(acc1, xb.y, w1);
      FMA4S(acc1, xb.z, w2); FMA4S(acc1, xb.w, w3);
    }
  }
  float* O = (m ? Pbuf : Abuf) + ((size_t)b * TT + r0) * HH;
  *(float4*)(O + (2 * rr) * 128 + h0)     = acc0;
  *(float4*)(O + (2 * rr + 1) * 128 + h0) = acc1;
}

// ---------------------------------------------------------------------------
// K3: attention + output. Block = (b, 16 decoder steps). 512 threads.
// t halved so LDS stays < 64 KB; P transposed into LDS with XOR-quad swizzle.
// ---------------------------------------------------------------------------
__global__ __launch_bounds__(512, 2) void attn_kernel(
    const float* __restrict__ encH, const float* __restrict__ decH,
    const float* __restrict__ Abuf, const float* __restrict__ Pbuf,
    const float* __restrict__ vw, const float* __restrict__ outW,
    const float* __restrict__ outb, float* __restrict__ out)
{
  const int b  = blockIdx.x >> 3;
  const int s0 = (blockIdx.x & 7) * 16;
  const int tid = threadIdx.x;

  __shared__ __align__(16) float buf[64 * 128];    // 32 KB: P^T-half (swizzled), later encH-half
  __shared__ __align__(16) float a_lds[16 * 128];  // 8 KB: A tile, later ctx
  __shared__ __align__(16) float sc[16 * 128];     // 8 KB: scores -> weights
  __shared__ __align__(16) float dh[16 * 128];     // 8 KB: decH tile
  __shared__ __align__(16) float vl[HH];

  ((float4*)a_lds)[tid] = ((const float4*)(Abuf + ((size_t)b * TT + s0) * HH))[tid];
  ((float4*)dh)[tid]    = ((const float4*)(decH + ((size_t)b * TT + s0) * HH))[tid];
  if (tid < 32) ((float4*)vl)[tid] = ((const float4*)vw)[tid];

  const int u  = tid & 31;
  const int sl = tid >> 5;   // 0..15 decoder-step within tile
  const int uq = u & 15;     // t-quad within half
  const int uh = u >> 4;     // 0/1 h-half

  // ---- energies/scores ----
  for (int half = 0; half < 2; ++half) {
    const int tbase = half * 64;
    __syncthreads();  // prev buf use done (also covers initial staging)
    #pragma unroll
    for (int i = 0; i < 4; ++i) {
      int flat = i * 2048 + tid * 4;
      int tp = flat >> 7;        // 0..63
      int h0 = flat & 127;
      float4 v = *(const float4*)(Pbuf + ((size_t)b * TT + tbase + tp) * HH + h0);
      int tq = tp >> 2, tr = tp & 3;
      buf[(h0 + 0) * 64 + 4 * ((tq ^ ((h0 + 0) >> 2)) & 15) + tr] = v.x;
      buf[(h0 + 1) * 64 + 4 * ((tq ^ ((h0 + 1) >> 2)) & 15) + tr] = v.y;
      buf[(h0 + 2) * 64 + 4 * ((tq ^ ((h0 + 2) >> 2)) & 15) + tr] = v.z;
      buf[(h0 + 3) * 64 + 4 * ((tq ^ ((h0 + 3) >> 2)) & 15) + tr] = v.w;
    }
    __syncthreads();
    float4 acc = make_float4(0.f, 0.f, 0.f, 0.f);
    const float* arow = a_lds + sl * 128;
    #pragma unroll 8
    for (int hh = 0; hh < 64; ++hh) {
      int h = uh * 64 + hh;
      float ah = arow[h];
      float vh = vl[h];
      float4 p4 = *(const float4*)&buf[h * 64 + 4 * ((uq ^ ((h >> 2) & 15)) & 15)];
      acc.x = fmaf(vh, tanh_f(ah + p4.x), acc.x);
      acc.y = fmaf(vh, tanh_f(ah + p4.y), acc.y);
      acc.z = fmaf(vh, tanh_f(ah + p4.z), acc.z);
      acc.w = fmaf(vh, tanh_f(ah + p4.w), acc.w);
    }
    acc.x += __shfl_xor(acc.x, 16, 64);
    acc.y += __shfl_xor(acc.y, 16, 64);
    acc.z += __shfl_xor(acc.z, 16, 64);
    acc.w += __shfl_xor(acc.w, 16, 64);
    if (uh == 0) *(float4*)&sc[sl * 128 + tbase + 4 * uq] = acc;
  }
  __syncthreads();

  // ---- softmax over t (per s row; 32 lanes x f4 = 128) ----
  {
    float4 sv = *(const float4*)&sc[sl * 128 + 4 * u];
    float mx = fmaxf(fmaxf(sv.x, sv.y), fmaxf(sv.z, sv.w));
    #pragma unroll
    for (int msk = 1; msk <= 16; msk <<= 1) mx = fmaxf(mx, __shfl_xor(mx, msk, 64));
    float4 e;
    e.x = fexp2(LOG2E * (sv.x - mx));
    e.y = fexp2(LOG2E * (sv.y - mx));
    e.z = fexp2(LOG2E * (sv.z - mx));
    e.w = fexp2(LOG2E * (sv.w - mx));
    float sm = (e.x + e.y) + (e.z + e.w);
    #pragma unroll
    for (int msk = 1; msk <= 16; msk <<= 1) sm += __shfl_xor(sm, msk, 64);
    float r = frcp(sm);
    e.x *= r; e.y *= r; e.z *= r; e.w *= r;
    *(float4*)&sc[sl * 128 + 4 * u] = e;
  }

  // ---- ctx = w @ encH ----
  float4 ctx = make_float4(0.f, 0.f, 0.f, 0.f);
  const int h0c = 4 * u;
  for (int half = 0; half < 2; ++half) {
    const int tbase = half * 64;
    __syncthreads();  // buf reuse; also orders softmax writes before reads
    #pragma unroll
    for (int i = 0; i < 4; ++i) {
      int flat = i * 2048 + tid * 4;
      int tp = flat >> 7;
      int hh0 = flat & 127;
      *(float4*)&buf[tp * 128 + hh0] =
          *(const float4*)(encH + ((size_t)b * TT + tbase + tp) * HH + hh0);
    }
    __syncthreads();
    const float* wrow = sc + sl * 128 + tbase;
    #pragma unroll 8
    for (int tp = 0; tp < 64; ++tp) {
      float wt = wrow[tp];
      float4 e4 = *(const float4*)&buf[tp * 128 + h0c];
      FMA4S(ctx, wt, e4);
    }
  }
  __syncthreads();
  *(float4*)&a_lds[sl * 128 + h0c] = ctx;  // overlay A tile with ctx
  __syncthreads();

  // ---- out = [decH, ctx] @ outW^T + outb ----
  if (tid < 192) {
    int s = tid / 12, f = tid % 12;
    float acc = outb[f];
    const float4* w4 = (const float4*)(outW + f * 256);
    const float4* d4 = (const float4*)(dh + s * 128);
    const float4* c4 = (const float4*)(a_lds + s * 128);
    #pragma unroll
    for (int k = 0; k < 32; ++k) {
      float4 wv = w4[k], dv = d4[k];
      acc = fmaf(wv.x, dv.x, acc); acc = fmaf(wv.y, dv.y, acc);
      acc = fmaf(wv.z, dv.z, acc); acc = fmaf(wv.w, dv.w, acc);
    }
    #pragma unroll
    for (int k = 0; k < 32; ++k) {
      float4 wv = w4[32 + k], cv = c4[k];
      acc = fmaf(wv.x, cv.x, acc); acc = fmaf(wv.y, cv.y, acc);
      acc = fmaf(wv.z, cv.z, acc); acc = fmaf(wv.w, cv.w, acc);
    }
    out[((size_t)b * TT + s0 + s) * FIN + f] = acc;
  }
}

// ---------------------------------------------------------------------------
extern "C" void kernel_launch(void* const* d_in, const int* in_sizes, int n_in,
                              void* d_out, int out_size, void* d_ws, size_t ws_size,
                              hipStream_t stream)
{
  const float* x     = (const float*)d_in[0];
  const float* eWih  = (const float*)d_in[1];
  const float* eWhh  = (const float*)d_in[2];
  const float* eb    = (const float*)d_in[3];
  const float* dWih  = (const float*)d_in[4];
  const float* dWhh  = (const float*)d_in[5];
  const float* db    = (const float*)d_in[6];
  const float* attnW = (const float*)d_in[7];
  const float* attnb = (const float*)d_in[8];
  const float* vw    = (const float*)d_in[9];
  const float* outW  = (const float*)d_in[10];
  const float* outb  = (const float*)d_in[11];
  float* out = (float*)d_out;

  float* ws   = (float*)d_ws;
  const size_t SEG = (size_t)BB * TT * HH;  // 1,048,576 floats = 4 MB
  float* encH = ws;
  float* decH = ws + SEG;
  float* Abuf = ws + 2 * SEG;
  float* Pbuf = ws + 3 * SEG;

  lstm_kernel<<<64, 256, 0, stream>>>(x, eWih, eWhh, eb, dWih, dWhh, db, encH, decH);
  proj_kernel<<<1024, 256, 0, stream>>>(encH, decH, attnW, attnb, Abuf, Pbuf);
  attn_kernel<<<512, 512, 0, stream>>>(encH, decH, Abuf, Pbuf, vw, outW, outb, out);
}

// Round 5
// 411.554 us; speedup vs baseline: 1.5408x; 1.5408x over previous
//
#include <hip/hip_runtime.h>
#include <hip/hip_bf16.h>

// Problem dims
#define BB 64
#define TT 128
#define FIN 12
#define HH 128
#define GG 512  // 4*H

#define LOG2E 1.4426950408889634f
#define TWO_LOG2E 2.8853900817779268f

__device__ __forceinline__ float fexp2(float x) { return __builtin_amdgcn_exp2f(x); }
__device__ __forceinline__ float frcp(float x)  { return __builtin_amdgcn_rcpf(x); }

// tanh(x) = 1 - 2/(1+e^{2x}); correct limits at +/-inf via exp2->{inf,0}
__device__ __forceinline__ float tanh_f(float x) {
  return 1.0f - 2.0f * frcp(1.0f + fexp2(TWO_LOG2E * x));
}
__device__ __forceinline__ float sigm_f(float x) {
  return frcp(1.0f + fexp2(-LOG2E * x));
}

// LDS-only barrier: drains this wave's LDS ops (lgkmcnt) then barriers.
// Unlike __syncthreads(), does NOT wait vmcnt(0) -- leaves the global h-store
// in flight, keeping the HBM/L2 store-ack off the 256x critical path.
// LDS visibility: each writer waits its own lgkmcnt before s_barrier, so
// post-barrier readers see committed LDS data (same mechanics as syncthreads).
__device__ __forceinline__ void bar_lds() {
  asm volatile("s_waitcnt lgkmcnt(0)\n\ts_barrier" ::: "memory");
}

#define FMA4S(acc, s, v) do { \
  acc.x = fmaf((s), (v).x, acc.x); \
  acc.y = fmaf((s), (v).y, acc.y); \
  acc.z = fmaf((s), (v).z, acc.z); \
  acc.w = fmaf((s), (v).w, acc.w); } while (0)

#define ACC4(hv, wv, a) do { \
  a = fmaf((hv).x, (wv).x, a); a = fmaf((hv).y, (wv).y, a); \
  a = fmaf((hv).z, (wv).z, a); a = fmaf((hv).w, (wv).w, a); } while (0)

// ---------------------------------------------------------------------------
// K1 v5 = R3 structure + two fixes from the R1-R4 post-mortems:
//  (a) __launch_bounds__(1024,2): 256-reg cap on the UNIFIED gfx950 file, so
//      the 64 weight floats live in arch VGPRs -- R3's (1024,4)=128-cap parked
//      them in AGPRs, costing one v_accvgpr_read per weight-FMA (the hidden
//      2x VALU inflation measured as 93% per-active-CU VALUBusy).
//  (b) bar_lds() instead of __syncthreads(): no vmcnt(0) drain of the global
//      h-store on every step's barrier.
// Layout (R3): thread (i = tid>>3, q = tid&7) owns all 4 gate rows of h-index
// i over k-slice [16q,16q+16) (64 weight floats), h skewed in LDS (16-float
// blocks padded to 20), shfl_xor partial reduce, q==0 lane updates (c,h).
// 1 barrier/step, double-buffered h.
// ---------------------------------------------------------------------------
__global__ __launch_bounds__(1024, 2) void lstm_kernel(
    const float* __restrict__ x,
    const float* __restrict__ eWih, const float* __restrict__ eWhh, const float* __restrict__ eb,
    const float* __restrict__ dWih, const float* __restrict__ dWhh, const float* __restrict__ db,
    float* __restrict__ encH, float* __restrict__ decH)
{
  const int b   = blockIdx.x;
  const int tid = threadIdx.x;
  const int q   = tid & 7;    // k-slice index
  const int i   = tid >> 3;   // h index 0..127

  __shared__ __align__(16) float xs[TT * FIN];   // 6 KB
  __shared__ __align__(16) float hbuf[2][160];   // skewed h, double-buffered

  if (tid < (TT * FIN / 4))
    ((float4*)xs)[tid] = ((const float4*)(x + (size_t)b * TT * FIN))[tid];
  if (tid < 320) ((float*)hbuf)[tid] = 0.0f;
  float c = 0.0f;  // live in q==0 lanes

  const int xo   = (q < 4) ? 3 * q : 0;   // in-bounds x offset
  const float xz = (q < 4) ? 1.0f : 0.0f;

  int ts = 0;
  #pragma unroll 1
  for (int phase = 0; phase < 2; ++phase) {
    const float* Wih  = phase ? dWih : eWih;
    const float* Whh  = phase ? dWhh : eWhh;
    const float* bias = phase ? db : eb;
    float* Hout       = phase ? decH : encH;

    // recurrent weights: 4 gates x 16 k (k = 16q + 4j + comp)
    float4 wg[4][4];
    #pragma unroll
    for (int g = 0; g < 4; ++g)
      #pragma unroll
      for (int j = 0; j < 4; ++j)
        wg[g][j] = *(const float4*)(Whh + ((g * HH + i) * HH) + 16 * q + 4 * j);

    // input weights: 3 columns (xo..xo+2) of each gate row; zero for q>=4
    float wx[4][3];
    #pragma unroll
    for (int g = 0; g < 4; ++g)
      #pragma unroll
      for (int j = 0; j < 3; ++j)
        wx[g][j] = Wih[(g * HH + i) * FIN + xo + j] * xz;

    const float bi = bias[i], bf = bias[HH + i], bg = bias[2 * HH + i], bo = bias[3 * HH + i];

    #pragma unroll 1
    for (int t = 0; t < TT; ++t, ++ts) {
      bar_lds();  // h(t) ready in hbuf[ts&1]; prev-step buffer reads done
      const float* hb = hbuf[ts & 1] + q * 20;
      float4 h0 = *(const float4*)(hb + 0);
      float4 h1 = *(const float4*)(hb + 4);
      float4 h2 = *(const float4*)(hb + 8);
      float4 h3 = *(const float4*)(hb + 12);

      // x contribution (q<4 lanes carry it; others have zero weights)
      const float* xt = xs + t * FIN + xo;
      float x0 = xt[0], x1 = xt[1], x2 = xt[2];
      float ai = wx[0][0] * x0 + wx[0][1] * x1 + wx[0][2] * x2;
      float af = wx[1][0] * x0 + wx[1][1] * x1 + wx[1][2] * x2;
      float ag = wx[2][0] * x0 + wx[2][1] * x1 + wx[2][2] * x2;
      float ao = wx[3][0] * x0 + wx[3][1] * x1 + wx[3][2] * x2;

      ACC4(h0, wg[0][0], ai); ACC4(h0, wg[1][0], af); ACC4(h0, wg[2][0], ag); ACC4(h0, wg[3][0], ao);
      ACC4(h1, wg[0][1], ai); ACC4(h1, wg[1][1], af); ACC4(h1, wg[2][1], ag); ACC4(h1, wg[3][1], ao);
      ACC4(h2, wg[0][2], ai); ACC4(h2, wg[1][2], af); ACC4(h2, wg[2][2], ag); ACC4(h2, wg[3][2], ao);
      ACC4(h3, wg[0][3], ai); ACC4(h3, wg[1][3], af); ACC4(h3, wg[2][3], ag); ACC4(h3, wg[3][3], ao);

      // reduce partials across the 8 q-lanes (lane bits 0-2)
      #pragma unroll
      for (int m = 1; m <= 4; m <<= 1) {
        ai += __shfl_xor(ai, m, 64);
        af += __shfl_xor(af, m, 64);
        ag += __shfl_xor(ag, m, 64);
        ao += __shfl_xor(ao, m, 64);
      }

      if (q == 0) {
        float zi = sigm_f(ai + bi);
        float zf = sigm_f(af + bf);
        float zg = tanh_f(ag + bg);
        float zo = sigm_f(ao + bo);
        c = fmaf(zf, c, zi * zg);
        float hn = zo * tanh_f(c);
        hbuf[(ts + 1) & 1][(i >> 4) * 20 + (i & 15)] = hn;
        Hout[((size_t)b * TT + t) * HH + i] = hn;  // stays in flight across bar_lds
      }
    }
  }
}

// ---------------------------------------------------------------------------
// K2: A[b,s,h] = decH[b,s,:]·W1[h,:] + attn_b[h]   (m==0)
//     P[b,t,h] = encH[b,t,:]·W2[h,:]               (m==1)
// grid 1024 = (8 row-tiles x 64 b x 2 m), 256 threads, k-halved LDS W^T.
// ---------------------------------------------------------------------------
__global__ __launch_bounds__(256, 2) void proj_kernel(
    const float* __restrict__ encH, const float* __restrict__ decH,
    const float* __restrict__ attnW, const float* __restrict__ attnb,
    float* __restrict__ Abuf, float* __restrict__ Pbuf)
{
  const int m  = blockIdx.x & 1;
  const int b  = (blockIdx.x >> 1) & 63;
  const int r0 = (blockIdx.x >> 7) * 16;
  const int tid = threadIdx.x;

  __shared__ __align__(16) float WT[64 * 128];  // 32 KB: W^T for a k-half
  __shared__ __align__(16) float Xt[16 * 128];  // 8 KB

  const float* X = (m ? encH : decH) + ((size_t)b * TT + r0) * HH;
  const float* W = attnW + (m ? HH : 0);

  ((float4*)Xt)[tid]       = ((const float4*)X)[tid];
  ((float4*)Xt)[256 + tid] = ((const float4*)X)[256 + tid];

  const int hq = tid & 31, rr = tid >> 5;
  const int h0 = 4 * hq;

  float4 acc0, acc1;
  if (m == 0) { acc0 = *(const float4*)(attnb + h0); acc1 = acc0; }
  else        { acc0 = make_float4(0.f, 0.f, 0.f, 0.f); acc1 = acc0; }

  for (int kb = 0; kb < 2; ++kb) {
    __syncthreads();  // protect WT overwrite
    {
      int h = tid >> 1, koff = (tid & 1) * 32;
      #pragma unroll
      for (int j = 0; j < 8; ++j) {
        float4 v = *(const float4*)(W + h * 256 + kb * 64 + koff + 4 * j);
        int kp = koff + 4 * j;
        WT[(kp + 0) * 128 + h] = v.x;
        WT[(kp + 1) * 128 + h] = v.y;
        WT[(kp + 2) * 128 + h] = v.z;
        WT[(kp + 3) * 128 + h] = v.w;
      }
    }
    __syncthreads();
    const float* xr0 = Xt + (2 * rr) * 128 + kb * 64;
    const float* xr1 = xr0 + 128;
    #pragma unroll
    for (int k4 = 0; k4 < 64; k4 += 4) {
      float4 xa = *(const float4*)(xr0 + k4);
      float4 xb = *(const float4*)(xr1 + k4);
      float4 w0 = *(const float4*)&WT[(k4 + 0) * 128 + h0];
      float4 w1 = *(const float4*)&WT[(k4 + 1) * 128 + h0];
      float4 w2 = *(const float4*)&WT[(k4 + 2) * 128 + h0];
      float4 w3 = *(const float4*)&WT[(k4 + 3) * 128 + h0];
      FMA4S(acc0, xa.x, w0); FMA4S(acc0, xa.y, w1);
      FMA4S(acc0, xa.z, w2); FMA4S(acc0, xa.w, w3);
      FMA4S(acc1, xb.x, w0); FMA4S(acc1, xb.y, w1);
      FMA4S(acc1, xb.z, w2); FMA4S(acc1, xb.w, w3);
    }
  }
  float* O = (m ? Pbuf : Abuf) + ((size_t)b * TT + r0) * HH;
  *(float4*)(O + (2 * rr) * 128 + h0)     = acc0;
  *(float4*)(O + (2 * rr + 1) * 128 + h0) = acc1;
}

// ---------------------------------------------------------------------------
// K3: attention + output. Block = (b, 16 decoder steps). 512 threads.
// t halved so LDS stays < 64 KB; P transposed into LDS with XOR-quad swizzle.
// ---------------------------------------------------------------------------
__global__ __launch_bounds__(512, 2) void attn_kernel(
    const float* __restrict__ encH, const float* __restrict__ decH,
    const float* __restrict__ Abuf, const float* __restrict__ Pbuf,
    const float* __restrict__ vw, const float* __restrict__ outW,
    const float* __restrict__ outb, float* __restrict__ out)
{
  const int b  = blockIdx.x >> 3;
  const int s0 = (blockIdx.x & 7) * 16;
  const int tid = threadIdx.x;

  __shared__ __align__(16) float buf[64 * 128];    // 32 KB: P^T-half (swizzled), later encH-half
  __shared__ __align__(16) float a_lds[16 * 128];  // 8 KB: A tile, later ctx
  __shared__ __align__(16) float sc[16 * 128];     // 8 KB: scores -> weights
  __shared__ __align__(16) float dh[16 * 128];     // 8 KB: decH tile
  __shared__ __align__(16) float vl[HH];

  ((float4*)a_lds)[tid] = ((const float4*)(Abuf + ((size_t)b * TT + s0) * HH))[tid];
  ((float4*)dh)[tid]    = ((const float4*)(decH + ((size_t)b * TT + s0) * HH))[tid];
  if (tid < 32) ((float4*)vl)[tid] = ((const float4*)vw)[tid];

  const int u  = tid & 31;
  const int sl = tid >> 5;   // 0..15 decoder-step within tile
  const int uq = u & 15;     // t-quad within half
  const int uh = u >> 4;     // 0/1 h-half

  // ---- energies/scores ----
  for (int half = 0; half < 2; ++half) {
    const int tbase = half * 64;
    __syncthreads();  // prev buf use done (also covers initial staging)
    #pragma unroll
    for (int i = 0; i < 4; ++i) {
      int flat = i * 2048 + tid * 4;
      int tp = flat >> 7;        // 0..63
      int h0 = flat & 127;
      float4 v = *(const float4*)(Pbuf + ((size_t)b * TT + tbase + tp) * HH + h0);
      int tq = tp >> 2, tr = tp & 3;
      buf[(h0 + 0) * 64 + 4 * ((tq ^ ((h0 + 0) >> 2)) & 15) + tr] = v.x;
      buf[(h0 + 1) * 64 + 4 * ((tq ^ ((h0 + 1) >> 2)) & 15) + tr] = v.y;
      buf[(h0 + 2) * 64 + 4 * ((tq ^ ((h0 + 2) >> 2)) & 15) + tr] = v.z;
      buf[(h0 + 3) * 64 + 4 * ((tq ^ ((h0 + 3) >> 2)) & 15) + tr] = v.w;
    }
    __syncthreads();
    float4 acc = make_float4(0.f, 0.f, 0.f, 0.f);
    const float* arow = a_lds + sl * 128;
    #pragma unroll 8
    for (int hh = 0; hh < 64; ++hh) {
      int h = uh * 64 + hh;
      float ah = arow[h];
      float vh = vl[h];
      float4 p4 = *(const float4*)&buf[h * 64 + 4 * ((uq ^ ((h >> 2) & 15)) & 15)];
      acc.x = fmaf(vh, tanh_f(ah + p4.x), acc.x);
      acc.y = fmaf(vh, tanh_f(ah + p4.y), acc.y);
      acc.z = fmaf(vh, tanh_f(ah + p4.z), acc.z);
      acc.w = fmaf(vh, tanh_f(ah + p4.w), acc.w);
    }
    acc.x += __shfl_xor(acc.x, 16, 64);
    acc.y += __shfl_xor(acc.y, 16, 64);
    acc.z += __shfl_xor(acc.z, 16, 64);
    acc.w += __shfl_xor(acc.w, 16, 64);
    if (uh == 0) *(float4*)&sc[sl * 128 + tbase + 4 * uq] = acc;
  }
  __syncthreads();

  // ---- softmax over t (per s row; 32 lanes x f4 = 128) ----
  {
    float4 sv = *(const float4*)&sc[sl * 128 + 4 * u];
    float mx = fmaxf(fmaxf(sv.x, sv.y), fmaxf(sv.z, sv.w));
    #pragma unroll
    for (int msk = 1; msk <= 16; msk <<= 1) mx = fmaxf(mx, __shfl_xor(mx, msk, 64));
    float4 e;
    e.x = fexp2(LOG2E * (sv.x - mx));
    e.y = fexp2(LOG2E * (sv.y - mx));
    e.z = fexp2(LOG2E * (sv.z - mx));
    e.w = fexp2(LOG2E * (sv.w - mx));
    float sm = (e.x + e.y) + (e.z + e.w);
    #pragma unroll
    for (int msk = 1; msk <= 16; msk <<= 1) sm += __shfl_xor(sm, msk, 64);
    float r = frcp(sm);
    e.x *= r; e.y *= r; e.z *= r; e.w *= r;
    *(float4*)&sc[sl * 128 + 4 * u] = e;
  }

  // ---- ctx = w @ encH ----
  float4 ctx = make_float4(0.f, 0.f, 0.f, 0.f);
  const int h0c = 4 * u;
  for (int half = 0; half < 2; ++half) {
    const int tbase = half * 64;
    __syncthreads();  // buf reuse; also orders softmax writes before reads
    #pragma unroll
    for (int i = 0; i < 4; ++i) {
      int flat = i * 2048 + tid * 4;
      int tp = flat >> 7;
      int hh0 = flat & 127;
      *(float4*)&buf[tp * 128 + hh0] =
          *(const float4*)(encH + ((size_t)b * TT + tbase + tp) * HH + hh0);
    }
    __syncthreads();
    const float* wrow = sc + sl * 128 + tbase;
    #pragma unroll 8
    for (int tp = 0; tp < 64; ++tp) {
      float wt = wrow[tp];
      float4 e4 = *(const float4*)&buf[tp * 128 + h0c];
      FMA4S(ctx, wt, e4);
    }
  }
  __syncthreads();
  *(float4*)&a_lds[sl * 128 + h0c] = ctx;  // overlay A tile with ctx
  __syncthreads();

  // ---- out = [decH, ctx] @ outW^T + outb ----
  if (tid < 192) {
    int s = tid / 12, f = tid % 12;
    float acc = outb[f];
    const float4* w4 = (const float4*)(outW + f * 256);
    const float4* d4 = (const float4*)(dh + s * 128);
    const float4* c4 = (const float4*)(a_lds + s * 128);
    #pragma unroll
    for (int k = 0; k < 32; ++k) {
      float4 wv = w4[k], dv = d4[k];
      acc = fmaf(wv.x, dv.x, acc); acc = fmaf(wv.y, dv.y, acc);
      acc = fmaf(wv.z, dv.z, acc); acc = fmaf(wv.w, dv.w, acc);
    }
    #pragma unroll
    for (int k = 0; k < 32; ++k) {
      float4 wv = w4[32 + k], cv = c4[k];
      acc = fmaf(wv.x, cv.x, acc); acc = fmaf(wv.y, cv.y, acc);
      acc = fmaf(wv.z, cv.z, acc); acc = fmaf(wv.w, cv.w, acc);
    }
    out[((size_t)b * TT + s0 + s) * FIN + f] = acc;
  }
}

// ---------------------------------------------------------------------------
extern "C" void kernel_launch(void* const* d_in, const int* in_sizes, int n_in,
                              void* d_out, int out_size, void* d_ws, size_t ws_size,
                              hipStream_t stream)
{
  const float* x     = (const float*)d_in[0];
  const float* eWih  = (const float*)d_in[1];
  const float* eWhh  = (const float*)d_in[2];
  const float* eb    = (const float*)d_in[3];
  const float* dWih  = (const float*)d_in[4];
  const float* dWhh  = (const float*)d_in[5];
  const float* db    = (const float*)d_in[6];
  const float* attnW = (const float*)d_in[7];
  const float* attnb = (const float*)d_in[8];
  const float* vw    = (const float*)d_in[9];
  const float* outW  = (const float*)d_in[10];
  const float* outb  = (const float*)d_in[11];
  float* out = (float*)d_out;

  float* ws   = (float*)d_ws;
  const size_t SEG = (size_t)BB * TT * HH;  // 1,048,576 floats = 4 MB
  float* encH = ws;
  float* decH = ws + SEG;
  float* Abuf = ws + 2 * SEG;
  float* Pbuf = ws + 3 * SEG;

  lstm_kernel<<<64, 1024, 0, stream>>>(x, eWih, eWhh, eb, dWih, dWhh, db, encH, decH);
  proj_kernel<<<1024, 256, 0, stream>>>(encH, decH, attnW, attnb, Abuf, Pbuf);
  attn_kernel<<<512, 512, 0, stream>>>(encH, decH, Abuf, Pbuf, vw, outW, outb, out);
}

// Round 6
// 338.540 us; speedup vs baseline: 1.8731x; 1.2157x over previous
//
#include <hip/hip_runtime.h>
#include <hip/hip_bf16.h>

// Problem dims
#define BB 64
#define TT 128
#define FIN 12
#define HH 128
#define GG 512  // 4*H

#define LOG2E 1.4426950408889634f
#define TWO_LOG2E 2.8853900817779268f

__device__ __forceinline__ float fexp2(float x) { return __builtin_amdgcn_exp2f(x); }
__device__ __forceinline__ float frcp(float x)  { return __builtin_amdgcn_rcpf(x); }

// tanh(x) = 1 - 2/(1+e^{2x}); correct limits at +/-inf via exp2->{inf,0}
__device__ __forceinline__ float tanh_f(float x) {
  return 1.0f - 2.0f * frcp(1.0f + fexp2(TWO_LOG2E * x));
}
__device__ __forceinline__ float sigm_f(float x) {
  return frcp(1.0f + fexp2(-LOG2E * x));
}

// DPP 8-lane sum (over lane bits 0..2): xor1 + xor2 via quad_perm, then
// lane^7 via row_half_mirror. Pure VALU -- no DS-pipe traffic (R3-R5 lesson:
// __shfl_xor lowers to ds_bpermute; 192 of them per step was the top cost).
template <int CTRL>
__device__ __forceinline__ float dpp_addstage(float v) {
  int s = __builtin_amdgcn_update_dpp(0, __float_as_int(v), CTRL, 0xF, 0xF, true);
  return v + __int_as_float(s);
}
__device__ __forceinline__ float red8(float v) {
  v = dpp_addstage<0xB1>(v);   // quad_perm [1,0,3,2]: partner lane^1
  v = dpp_addstage<0x4E>(v);   // quad_perm [2,3,0,1]: partner lane^2
  v = dpp_addstage<0x141>(v);  // row_half_mirror: partner lane^7 -> 8-lane total
  return v;
}

#define FMA4S(acc, s, v) do { \
  acc.x = fmaf((s), (v).x, acc.x); \
  acc.y = fmaf((s), (v).y, acc.y); \
  acc.z = fmaf((s), (v).z, acc.z); \
  acc.w = fmaf((s), (v).w, acc.w); } while (0)

#define ACC4(hv, wv, a) do { \
  a = fmaf((hv).x, (wv).x, a); a = fmaf((hv).y, (wv).y, a); \
  a = fmaf((hv).z, (wv).z, a); a = fmaf((hv).w, (wv).w, a); } while (0)

// ---------------------------------------------------------------------------
// K1 v6 = R3 structure (best so far, 237us) + two DS-pipe cuts:
//  (a) shfl_xor -> DPP reduce (VALU): removes 192 ds_bpermute per step.
//  (b) h history staged in LDS (32 KB, 64 steps), bulk-copied to global every
//      64 steps: the step loop has ZERO vm ops, so __syncthreads' vmcnt(0)
//      drain is free (R3 paid a global-store ack every step).
// Layout: thread (i = tid>>3, q = tid&7) owns all 4 gate rows of h-index i
// over k-slice [16q,16q+16); h skewed (16-float blocks padded to 20);
// q==0 lane applies activations, updates (c,h). 1 barrier/step.
// ---------------------------------------------------------------------------
__global__ __launch_bounds__(1024, 4) void lstm_kernel(
    const float* __restrict__ x,
    const float* __restrict__ eWih, const float* __restrict__ eWhh, const float* __restrict__ eb,
    const float* __restrict__ dWih, const float* __restrict__ dWhh, const float* __restrict__ db,
    float* __restrict__ encH, float* __restrict__ decH)
{
  const int b   = blockIdx.x;
  const int tid = threadIdx.x;
  const int q   = tid & 7;    // k-slice index
  const int i   = tid >> 3;   // h index 0..127

  __shared__ __align__(16) float xs[TT * FIN];     // 6 KB
  __shared__ __align__(16) float hbuf[2][160];     // skewed h, double-buffered
  __shared__ __align__(16) float hist[64 * HH];    // 32 KB: 64-step h history

  if (tid < (TT * FIN / 4))
    ((float4*)xs)[tid] = ((const float4*)(x + (size_t)b * TT * FIN))[tid];
  if (tid < 320) ((float*)hbuf)[tid] = 0.0f;
  float c = 0.0f;  // live in q==0 lanes

  const int xo   = (q < 4) ? 3 * q : 0;   // in-bounds x offset
  const float xz = (q < 4) ? 1.0f : 0.0f;

  int ts = 0;
  #pragma unroll 1
  for (int phase = 0; phase < 2; ++phase) {
    const float* Wih  = phase ? dWih : eWih;
    const float* Whh  = phase ? dWhh : eWhh;
    const float* bias = phase ? db : eb;
    float* Hout       = phase ? decH : encH;

    // recurrent weights: 4 gates x 16 k (k = 16q + 4j + comp)
    float4 wg[4][4];
    #pragma unroll
    for (int g = 0; g < 4; ++g)
      #pragma unroll
      for (int j = 0; j < 4; ++j)
        wg[g][j] = *(const float4*)(Whh + ((g * HH + i) * HH) + 16 * q + 4 * j);

    // input weights: 3 columns (xo..xo+2) of each gate row; zero for q>=4
    float wx[4][3];
    #pragma unroll
    for (int g = 0; g < 4; ++g)
      #pragma unroll
      for (int j = 0; j < 3; ++j)
        wx[g][j] = Wih[(g * HH + i) * FIN + xo + j] * xz;

    const float bi = bias[i], bf = bias[HH + i], bg = bias[2 * HH + i], bo = bias[3 * HH + i];

    #pragma unroll 1
    for (int half = 0; half < 2; ++half) {
      #pragma unroll 1
      for (int tt = 0; tt < 64; ++tt, ++ts) {
        const int t = half * 64 + tt;
        __syncthreads();  // h(t) ready in hbuf[ts&1]; hist copy reads done
        const float* hb = hbuf[ts & 1] + q * 20;
        float4 h0 = *(const float4*)(hb + 0);
        float4 h1 = *(const float4*)(hb + 4);
        float4 h2 = *(const float4*)(hb + 8);
        float4 h3 = *(const float4*)(hb + 12);

        // x contribution (q<4 lanes carry it; others have zero weights)
        const float* xt = xs + t * FIN + xo;
        float x0 = xt[0], x1 = xt[1], x2 = xt[2];
        float ai = wx[0][0] * x0 + wx[0][1] * x1 + wx[0][2] * x2;
        float af = wx[1][0] * x0 + wx[1][1] * x1 + wx[1][2] * x2;
        float ag = wx[2][0] * x0 + wx[2][1] * x1 + wx[2][2] * x2;
        float ao = wx[3][0] * x0 + wx[3][1] * x1 + wx[3][2] * x2;

        ACC4(h0, wg[0][0], ai); ACC4(h0, wg[1][0], af); ACC4(h0, wg[2][0], ag); ACC4(h0, wg[3][0], ao);
        ACC4(h1, wg[0][1], ai); ACC4(h1, wg[1][1], af); ACC4(h1, wg[2][1], ag); ACC4(h1, wg[3][1], ao);
        ACC4(h2, wg[0][2], ai); ACC4(h2, wg[1][2], af); ACC4(h2, wg[2][2], ag); ACC4(h2, wg[3][2], ao);
        ACC4(h3, wg[0][3], ai); ACC4(h3, wg[1][3], af); ACC4(h3, wg[2][3], ag); ACC4(h3, wg[3][3], ao);

        // reduce partials across the 8 q-lanes -- pure DPP (VALU)
        ai = red8(ai); af = red8(af); ag = red8(ag); ao = red8(ao);

        if (q == 0) {
          float zi = sigm_f(ai + bi);
          float zf = sigm_f(af + bf);
          float zg = tanh_f(ag + bg);
          float zo = sigm_f(ao + bo);
          c = fmaf(zf, c, zi * zg);
          float hn = zo * tanh_f(c);
          hbuf[(ts + 1) & 1][(i >> 4) * 20 + (i & 15)] = hn;
          hist[tt * HH + i] = hn;   // LDS only -- no vm op in the step loop
        }
      }
      // bulk-copy this half's history to global (64*128 floats = 2048 f4)
      __syncthreads();  // hist writes visible
      {
        float4* dst = (float4*)(Hout + ((size_t)b * TT + half * 64) * HH);
        const float4* src = (const float4*)hist;
        dst[tid]        = src[tid];
        dst[tid + 1024] = src[tid + 1024];
      }
      // next half's top-of-loop __syncthreads orders hist reuse; its vmcnt
      // drain absorbs the copy stores once per 64 steps.
    }
  }
}

// ---------------------------------------------------------------------------
// K2: A[b,s,h] = decH[b,s,:]·W1[h,:] + attn_b[h]   (m==0)
//     P[b,t,h] = encH[b,t,:]·W2[h,:]               (m==1)
// grid 1024 = (8 row-tiles x 64 b x 2 m), 256 threads, k-halved LDS W^T.
// ---------------------------------------------------------------------------
__global__ __launch_bounds__(256, 2) void proj_kernel(
    const float* __restrict__ encH, const float* __restrict__ decH,
    const float* __restrict__ attnW, const float* __restrict__ attnb,
    float* __restrict__ Abuf, float* __restrict__ Pbuf)
{
  const int m  = blockIdx.x & 1;
  const int b  = (blockIdx.x >> 1) & 63;
  const int r0 = (blockIdx.x >> 7) * 16;
  const int tid = threadIdx.x;

  __shared__ __align__(16) float WT[64 * 128];  // 32 KB: W^T for a k-half
  __shared__ __align__(16) float Xt[16 * 128];  // 8 KB

  const float* X = (m ? encH : decH) + ((size_t)b * TT + r0) * HH;
  const float* W = attnW + (m ? HH : 0);

  ((float4*)Xt)[tid]       = ((const float4*)X)[tid];
  ((float4*)Xt)[256 + tid] = ((const float4*)X)[256 + tid];

  const int hq = tid & 31, rr = tid >> 5;
  const int h0 = 4 * hq;

  float4 acc0, acc1;
  if (m == 0) { acc0 = *(const float4*)(attnb + h0); acc1 = acc0; }
  else        { acc0 = make_float4(0.f, 0.f, 0.f, 0.f); acc1 = acc0; }

  for (int kb = 0; kb < 2; ++kb) {
    __syncthreads();  // protect WT overwrite
    {
      int h = tid >> 1, koff = (tid & 1) * 32;
      #pragma unroll
      for (int j = 0; j < 8; ++j) {
        float4 v = *(const float4*)(W + h * 256 + kb * 64 + koff + 4 * j);
        int kp = koff + 4 * j;
        WT[(kp + 0) * 128 + h] = v.x;
        WT[(kp + 1) * 128 + h] = v.y;
        WT[(kp + 2) * 128 + h] = v.z;
        WT[(kp + 3) * 128 + h] = v.w;
      }
    }
    __syncthreads();
    const float* xr0 = Xt + (2 * rr) * 128 + kb * 64;
    const float* xr1 = xr0 + 128;
    #pragma unroll
    for (int k4 = 0; k4 < 64; k4 += 4) {
      float4 xa = *(const float4*)(xr0 + k4);
      float4 xb = *(const float4*)(xr1 + k4);
      float4 w0 = *(const float4*)&WT[(k4 + 0) * 128 + h0];
      float4 w1 = *(const float4*)&WT[(k4 + 1) * 128 + h0];
      float4 w2 = *(const float4*)&WT[(k4 + 2) * 128 + h0];
      float4 w3 = *(const float4*)&WT[(k4 + 3) * 128 + h0];
      FMA4S(acc0, xa.x, w0); FMA4S(acc0, xa.y, w1);
      FMA4S(acc0, xa.z, w2); FMA4S(acc0, xa.w, w3);
      FMA4S(acc1, xb.x, w0); FMA4S(acc1, xb.y, w1);
      FMA4S(acc1, xb.z, w2); FMA4S(acc1, xb.w, w3);
    }
  }
  float* O = (m ? Pbuf : Abuf) + ((size_t)b * TT + r0) * HH;
  *(float4*)(O + (2 * rr) * 128 + h0)     = acc0;
  *(float4*)(O + (2 * rr + 1) * 128 + h0) = acc1;
}

// ---------------------------------------------------------------------------
// K3: attention + output. Block = (b, 16 decoder steps). 512 threads.
// t halved so LDS stays < 64 KB; P transposed into LDS with XOR-quad swizzle.
// ---------------------------------------------------------------------------
__global__ __launch_bounds__(512, 2) void attn_kernel(
    const float* __restrict__ encH, const float* __restrict__ decH,
    const float* __restrict__ Abuf, const float* __restrict__ Pbuf,
    const float* __restrict__ vw, const float* __restrict__ outW,
    const float* __restrict__ outb, float* __restrict__ out)
{
  const int b  = blockIdx.x >> 3;
  const int s0 = (blockIdx.x & 7) * 16;
  const int tid = threadIdx.x;

  __shared__ __align__(16) float buf[64 * 128];    // 32 KB: P^T-half (swizzled), later encH-half
  __shared__ __align__(16) float a_lds[16 * 128];  // 8 KB: A tile, later ctx
  __shared__ __align__(16) float sc[16 * 128];     // 8 KB: scores -> weights
  __shared__ __align__(16) float dh[16 * 128];     // 8 KB: decH tile
  __shared__ __align__(16) float vl[HH];

  ((float4*)a_lds)[tid] = ((const float4*)(Abuf + ((size_t)b * TT + s0) * HH))[tid];
  ((float4*)dh)[tid]    = ((const float4*)(decH + ((size_t)b * TT + s0) * HH))[tid];
  if (tid < 32) ((float4*)vl)[tid] = ((const float4*)vw)[tid];

  const int u  = tid & 31;
  const int sl = tid >> 5;   // 0..15 decoder-step within tile
  const int uq = u & 15;     // t-quad within half
  const int uh = u >> 4;     // 0/1 h-half

  // ---- energies/scores ----
  for (int half = 0; half < 2; ++half) {
    const int tbase = half * 64;
    __syncthreads();  // prev buf use done (also covers initial staging)
    #pragma unroll
    for (int i = 0; i < 4; ++i) {
      int flat = i * 2048 + tid * 4;
      int tp = flat >> 7;        // 0..63
      int h0 = flat & 127;
      float4 v = *(const float4*)(Pbuf + ((size_t)b * TT + tbase + tp) * HH + h0);
      int tq = tp >> 2, tr = tp & 3;
      buf[(h0 + 0) * 64 + 4 * ((tq ^ ((h0 + 0) >> 2)) & 15) + tr] = v.x;
      buf[(h0 + 1) * 64 + 4 * ((tq ^ ((h0 + 1) >> 2)) & 15) + tr] = v.y;
      buf[(h0 + 2) * 64 + 4 * ((tq ^ ((h0 + 2) >> 2)) & 15) + tr] = v.z;
      buf[(h0 + 3) * 64 + 4 * ((tq ^ ((h0 + 3) >> 2)) & 15) + tr] = v.w;
    }
    __syncthreads();
    float4 acc = make_float4(0.f, 0.f, 0.f, 0.f);
    const float* arow = a_lds + sl * 128;
    #pragma unroll 8
    for (int hh = 0; hh < 64; ++hh) {
      int h = uh * 64 + hh;
      float ah = arow[h];
      float vh = vl[h];
      float4 p4 = *(const float4*)&buf[h * 64 + 4 * ((uq ^ ((h >> 2) & 15)) & 15)];
      acc.x = fmaf(vh, tanh_f(ah + p4.x), acc.x);
      acc.y = fmaf(vh, tanh_f(ah + p4.y), acc.y);
      acc.z = fmaf(vh, tanh_f(ah + p4.z), acc.z);
      acc.w = fmaf(vh, tanh_f(ah + p4.w), acc.w);
    }
    acc.x += __shfl_xor(acc.x, 16, 64);
    acc.y += __shfl_xor(acc.y, 16, 64);
    acc.z += __shfl_xor(acc.z, 16, 64);
    acc.w += __shfl_xor(acc.w, 16, 64);
    if (uh == 0) *(float4*)&sc[sl * 128 + tbase + 4 * uq] = acc;
  }
  __syncthreads();

  // ---- softmax over t (per s row; 32 lanes x f4 = 128) ----
  {
    float4 sv = *(const float4*)&sc[sl * 128 + 4 * u];
    float mx = fmaxf(fmaxf(sv.x, sv.y), fmaxf(sv.z, sv.w));
    #pragma unroll
    for (int msk = 1; msk <= 16; msk <<= 1) mx = fmaxf(mx, __shfl_xor(mx, msk, 64));
    float4 e;
    e.x = fexp2(LOG2E * (sv.x - mx));
    e.y = fexp2(LOG2E * (sv.y - mx));
    e.z = fexp2(LOG2E * (sv.z - mx));
    e.w = fexp2(LOG2E * (sv.w - mx));
    float sm = (e.x + e.y) + (e.z + e.w);
    #pragma unroll
    for (int msk = 1; msk <= 16; msk <<= 1) sm += __shfl_xor(sm, msk, 64);
    float r = frcp(sm);
    e.x *= r; e.y *= r; e.z *= r; e.w *= r;
    *(float4*)&sc[sl * 128 + 4 * u] = e;
  }

  // ---- ctx = w @ encH ----
  float4 ctx = make_float4(0.f, 0.f, 0.f, 0.f);
  const int h0c = 4 * u;
  for (int half = 0; half < 2; ++half) {
    const int tbase = half * 64;
    __syncthreads();  // buf reuse; also orders softmax writes before reads
    #pragma unroll
    for (int i = 0; i < 4; ++i) {
      int flat = i * 2048 + tid * 4;
      int tp = flat >> 7;
      int hh0 = flat & 127;
      *(float4*)&buf[tp * 128 + hh0] =
          *(const float4*)(encH + ((size_t)b * TT + tbase + tp) * HH + hh0);
    }
    __syncthreads();
    const float* wrow = sc + sl * 128 + tbase;
    #pragma unroll 8
    for (int tp = 0; tp < 64; ++tp) {
      float wt = wrow[tp];
      float4 e4 = *(const float4*)&buf[tp * 128 + h0c];
      FMA4S(ctx, wt, e4);
    }
  }
  __syncthreads();
  *(float4*)&a_lds[sl * 128 + h0c] = ctx;  // overlay A tile with ctx
  __syncthreads();

  // ---- out = [decH, ctx] @ outW^T + outb ----
  if (tid < 192) {
    int s = tid / 12, f = tid % 12;
    float acc = outb[f];
    const float4* w4 = (const float4*)(outW + f * 256);
    const float4* d4 = (const float4*)(dh + s * 128);
    const float4* c4 = (const float4*)(a_lds + s * 128);
    #pragma unroll
    for (int k = 0; k < 32; ++k) {
      float4 wv = w4[k], dv = d4[k];
      acc = fmaf(wv.x, dv.x, acc); acc = fmaf(wv.y, dv.y, acc);
      acc = fmaf(wv.z, dv.z, acc); acc = fmaf(wv.w, dv.w, acc);
    }
    #pragma unroll
    for (int k = 0; k < 32; ++k) {
      float4 wv = w4[32 + k], cv = c4[k];
      acc = fmaf(wv.x, cv.x, acc); acc = fmaf(wv.y, cv.y, acc);
      acc = fmaf(wv.z, cv.z, acc); acc = fmaf(wv.w, cv.w, acc);
    }
    out[((size_t)b * TT + s0 + s) * FIN + f] = acc;
  }
}

// ---------------------------------------------------------------------------
extern "C" void kernel_launch(void* const* d_in, const int* in_sizes, int n_in,
                              void* d_out, int out_size, void* d_ws, size_t ws_size,
                              hipStream_t stream)
{
  const float* x     = (const float*)d_in[0];
  const float* eWih  = (const float*)d_in[1];
  const float* eWhh  = (const float*)d_in[2];
  const float* eb    = (const float*)d_in[3];
  const float* dWih  = (const float*)d_in[4];
  const float* dWhh  = (const float*)d_in[5];
  const float* db    = (const float*)d_in[6];
  const float* attnW = (const float*)d_in[7];
  const float* attnb = (const float*)d_in[8];
  const float* vw    = (const float*)d_in[9];
  const float* outW  = (const float*)d_in[10];
  const float* outb  = (const float*)d_in[11];
  float* out = (float*)d_out;

  float* ws   = (float*)d_ws;
  const size_t SEG = (size_t)BB * TT * HH;  // 1,048,576 floats = 4 MB
  float* encH = ws;
  float* decH = ws + SEG;
  float* Abuf = ws + 2 * SEG;
  float* Pbuf = ws + 3 * SEG;

  lstm_kernel<<<64, 1024, 0, stream>>>(x, eWih, eWhh, eb, dWih, dWhh, db, encH, decH);
  proj_kernel<<<1024, 256, 0, stream>>>(encH, decH, attnW, attnb, Abuf, Pbuf);
  attn_kernel<<<512, 512, 0, stream>>>(encH, decH, Abuf, Pbuf, vw, outW, outb, out);
}